// Round 11
// baseline (405.876 us; speedup 1.0000x reference)
//
#include <hip/hip_runtime.h>

typedef __bf16 bf16_t;
typedef bf16_t bf16x8 __attribute__((ext_vector_type(8)));
typedef bf16_t bf16x4 __attribute__((ext_vector_type(4)));
typedef float f32x4 __attribute__((ext_vector_type(4)));
typedef unsigned short u16;
typedef unsigned int u32;

#define E_TOT 524288
#define MT 64
#define TPB 8                      // tiles per block
#define NBLK (E_TOT / (MT * TPB))  // 1024 = 4 blocks/CU exact fill

__device__ __forceinline__ u16 f2bf(float f) {
  u32 u = __builtin_bit_cast(u32, f);
  u += 0x7FFFu + ((u >> 16) & 1u);
  return (u16)(u >> 16);
}

__device__ __forceinline__ bf16x8 pack8(f32x4 a, f32x4 b) {
  bf16x8 p;
  p[0] = (bf16_t)a[0]; p[1] = (bf16_t)a[1]; p[2] = (bf16_t)a[2]; p[3] = (bf16_t)a[3];
  p[4] = (bf16_t)b[0]; p[5] = (bf16_t)b[1]; p[6] = (bf16_t)b[2]; p[7] = (bf16_t)b[3];
  return p;
}

// W1F frag-ordered: idx = (((kb*4+wc)*4+nf)*64+l)*8+e   (kb = 32-wide k-chunk, 0..11)
//   holds W1^T[n=wc*64+nf*16+(l&15)][k=kb*32+(l>>4)*8+e] = W1[k*256+n]
__global__ void prep_w1f(const float* __restrict__ W1, u16* __restrict__ W1F) {
  int t = blockIdx.x * 256 + threadIdx.x;
  if (t < 98304) {
    int e  = t & 7;
    int l  = (t >> 3) & 63;
    int nf = (t >> 9) & 3;
    int wc = (t >> 11) & 3;
    int kb = t >> 13;
    int n = wc * 64 + nf * 16 + (l & 15);
    int k = kb * 32 + ((l >> 4) << 3) + e;
    W1F[t] = f2bf(W1[k * 256 + n]);
  }
}

// W2F frag-ordered: idx = ((ks*4+n2f)*64+l)*8+e
//   holds W2^T[n2=n2f*16+(l&15)][k=ks*32+(l>>4)*8+e] = W2[k*64+n2]
__global__ void prep_w2f(const float* __restrict__ W2, u16* __restrict__ W2F) {
  int t = blockIdx.x * 256 + threadIdx.x;
  if (t < 16384) {
    int e   = t & 7;
    int l   = (t >> 3) & 63;
    int n2f = (t >> 9) & 3;
    int ks  = t >> 11;
    int n2 = n2f * 16 + (l & 15);
    int k  = ks * 32 + ((l >> 4) << 3) + e;
    W2F[t] = f2bf(W2[k * 64 + n2]);
  }
}

// Fused: x = [src|dest|edge|u[batch]] (E x 384); h = relu(x@W1+b1); out = h@W2+b2
// Swapped layer-1: acc = mfma(W_frag, x_frag) -> h^T fragments. 8 tiles/block, persistent.
__global__ void __launch_bounds__(256) edge_fused(
    const float* __restrict__ src, const float* __restrict__ dst,
    const float* __restrict__ ea, const float* __restrict__ u,
    const int* __restrict__ batch, const u16* __restrict__ W1F,
    const float* __restrict__ b1, const u16* __restrict__ W2F,
    const float* __restrict__ b2, float* __restrict__ out)
{
  // 32768 B LDS. K-loop: As dbuf 2 x 4096 u16 (4096-u16 stride — R10's bug was 2048).
  // Epilogue: Hs[64][256] (16384 u16) fully overlays As; overlay guarded by barriers.
  __shared__ __align__(16) u16 smem[16384];
  u16* As = smem;
  u16* Hs = smem;

  const int t    = threadIdx.x;
  const int wid  = t >> 6;
  const int lane = t & 63;
  const int lr   = lane & 15;
  const int lg   = lane >> 4;
  const int r    = t >> 2;        // A row owned by this thread (0..63)
  const int jc   = t & 3;         // 16-f32 col group within 64-k chunk
  const int u0   = 2 * jc;        // thread's two 16B units within the row
  const int eb0  = blockIdx.x * (MT * TPB);

  auto loadA = [&](int c, int ebase, f32x4* ra) {   // c is compile-time
    size_t er = (size_t)(ebase + r);
    const float* p;
    if (c < 2)       p = src + er * 128 + c * 64 + jc * 16;
    else if (c < 4)  p = dst + er * 128 + (c - 2) * 64 + jc * 16;
    else if (c == 4) p = ea + er * 64 + jc * 16;
    else             p = u + (size_t)batch[er] * 64 + jc * 16;
    ra[0] = *(const f32x4*)p;
    ra[1] = *(const f32x4*)(p + 4);
    ra[2] = *(const f32x4*)(p + 8);
    ra[3] = *(const f32x4*)(p + 12);
  };
  auto loadW1 = [&](int c, bf16x8* wf) {            // c is compile-time
    #pragma unroll
    for (int ks = 0; ks < 2; ++ks) {
      const u16* p = W1F + ((size_t)((2 * c + ks) * 4 + wid) * 4) * 512 + lane * 8;
      wf[ks * 4 + 0] = *(const bf16x8*)(p);
      wf[ks * 4 + 1] = *(const bf16x8*)(p + 512);
      wf[ks * 4 + 2] = *(const bf16x8*)(p + 1024);
      wf[ks * 4 + 3] = *(const bf16x8*)(p + 1536);
    }
  };

  // prologue: A chunks 0,1 of tile 0 + W chunk 0 in flight
  f32x4 ra[4], rb[4];
  bf16x8 wf[8];
  loadA(0, eb0, ra);
  loadA(1, eb0, rb);
  loadW1(0, wf);

  for (int tile = 0; tile < TPB; ++tile) {
    const int eb = eb0 + tile * MT;

    f32x4 acc[4][4];   // [nf][mf] h^T frags, re-zeroed per tile
    #pragma unroll
    for (int i = 0; i < 4; ++i)
      #pragma unroll
      for (int j = 0; j < 4; ++j)
        acc[i][j] = (f32x4){0.f, 0.f, 0.f, 0.f};

    // ---- K loop: 6 chunks of 64; one barrier/chunk; prefetches span tiles ----
    #pragma unroll
    for (int c = 0; c < 6; ++c) {
      f32x4* cur = (c & 1) ? rb : ra;       // 6 even -> parity is compile-time
      u16* Ab = As + (c & 1) * 4096;        // FIXED: full 4096-u16 buffer stride

      // pack + write A chunk c (2 swizzled b128 ds_writes)
      {
        bf16x8 lo = pack8(cur[0], cur[1]);
        bf16x8 hi = pack8(cur[2], cur[3]);
        *(bf16x8*)&Ab[(r * 8 + (u0 ^ (r & 7))) * 8]       = lo;
        *(bf16x8*)&Ab[(r * 8 + ((u0 + 1) ^ (r & 7))) * 8] = hi;
      }
      // depth-2 A prefetch (wraps into next tile at c=4,5)
      if (c < 4)            loadA(c + 2, eb, cur);
      else if (tile < TPB - 1) {
        if (c == 4) loadA(0, eb + MT, cur);
        else        loadA(1, eb + MT, cur);
      }

      // publish LDS writes only; global prefetches stay in flight
      asm volatile("s_waitcnt lgkmcnt(0)" ::: "memory");
      __builtin_amdgcn_s_barrier();
      __builtin_amdgcn_sched_barrier(0);

      __builtin_amdgcn_s_setprio(1);
      #pragma unroll
      for (int ks = 0; ks < 2; ++ks) {
        bf16x8 af[4];
        #pragma unroll
        for (int mf = 0; mf < 4; ++mf) {
          int row = mf * 16 + lr;
          af[mf] = *(const bf16x8*)&Ab[(row * 8 + ((ks * 4 + lg) ^ (row & 7))) * 8];
        }
        #pragma unroll
        for (int nf = 0; nf < 4; ++nf)
          #pragma unroll
          for (int mf = 0; mf < 4; ++mf)
            acc[nf][mf] = __builtin_amdgcn_mfma_f32_16x16x32_bf16(wf[ks * 4 + nf], af[mf], acc[nf][mf], 0, 0, 0);
      }
      __builtin_amdgcn_s_setprio(0);

      // W refill after last use (register dep orders it); wraps to chunk 0
      if (c < 5)                loadW1(c + 1, wf);
      else if (tile < TPB - 1)  loadW1(0, wf);
    }

    // drain all waves' chunk-5 As reads before Hs overlays the As region
    asm volatile("s_waitcnt lgkmcnt(0)" ::: "memory");
    __builtin_amdgcn_s_barrier();
    __builtin_amdgcn_sched_barrier(0);

    // ---- h^T -> Hs[64][256] bf16; 8B-unit swizzle up = uu ^ ((lr&3)<<2) ----
    #pragma unroll
    for (int nf = 0; nf < 4; ++nf) {
      f32x4 b1v = *(const f32x4*)(b1 + wid * 64 + nf * 16 + lg * 4);
      #pragma unroll
      for (int mf = 0; mf < 4; ++mf) {
        bf16x4 hb;
        #pragma unroll
        for (int rr = 0; rr < 4; ++rr)
          hb[rr] = (bf16_t)fmaxf(acc[nf][mf][rr] + b1v[rr], 0.f);
        int row = mf * 16 + lr;
        int uu = (wid * 4 + nf) * 4 + lg;
        int up = uu ^ ((lr & 3) << 2);
        *(bf16x4*)&Hs[row * 256 + up * 4] = hb;
      }
    }
    asm volatile("s_waitcnt lgkmcnt(0)" ::: "memory");
    __builtin_amdgcn_s_barrier();
    __builtin_amdgcn_sched_barrier(0);

    // ---- layer 2: out^T frags = mfma(W2_frag, h_frag); W2 from L1 (hot) ----
    const int row2 = wid * 16 + lr;
    f32x4 d2[4];
    #pragma unroll
    for (int i = 0; i < 4; ++i) d2[i] = (f32x4){0.f, 0.f, 0.f, 0.f};
    #pragma unroll
    for (int ks = 0; ks < 8; ++ks) {
      int uu = ks * 8 + lg * 2;
      int up = uu ^ ((lr & 3) << 2);     // bit0 untouched -> 16B stays contiguous
      bf16x8 a2 = *(const bf16x8*)&Hs[row2 * 256 + up * 4];
      const u16* q = W2F + (size_t)ks * 2048 + lane * 8;
      #pragma unroll
      for (int n2f = 0; n2f < 4; ++n2f)
        d2[n2f] = __builtin_amdgcn_mfma_f32_16x16x32_bf16(
            *(const bf16x8*)(q + n2f * 512), a2, d2[n2f], 0, 0, 0);
    }

    #pragma unroll
    for (int n2f = 0; n2f < 4; ++n2f) {
      f32x4 b2v = *(const f32x4*)(b2 + n2f * 16 + lg * 4);
      f32x4 ov = d2[n2f] + b2v;
      *(f32x4*)&out[(size_t)(eb + row2) * 64 + n2f * 16 + lg * 4] = ov;
    }

    // drain all waves' Hs reads before next tile's As writes reuse the region
    asm volatile("s_waitcnt lgkmcnt(0)" ::: "memory");
    __builtin_amdgcn_s_barrier();
    __builtin_amdgcn_sched_barrier(0);
  }
}

extern "C" void kernel_launch(void* const* d_in, const int* in_sizes, int n_in,
                              void* d_out, int out_size, void* d_ws, size_t ws_size,
                              hipStream_t stream) {
  const float* src  = (const float*)d_in[0];
  const float* dst  = (const float*)d_in[1];
  const float* ea   = (const float*)d_in[2];
  const float* u    = (const float*)d_in[3];
  const int* batch  = (const int*)d_in[4];
  const float* W1   = (const float*)d_in[5];
  const float* b1   = (const float*)d_in[6];
  const float* W2   = (const float*)d_in[7];
  const float* b2   = (const float*)d_in[8];
  float* out = (float*)d_out;

  u16* W1F = (u16*)d_ws;          // 98304 u16 frag-ordered W1^T
  u16* W2F = W1F + 98304;         // 16384 u16 frag-ordered W2^T

  prep_w1f<<<384, 256, 0, stream>>>(W1, W1F);
  prep_w2f<<<64, 256, 0, stream>>>(W2, W2F);
  edge_fused<<<NBLK, 256, 0, stream>>>(src, dst, ea, u, batch, W1F, b1, W2F, b2, out);
}

// Round 12
// 285.959 us; speedup vs baseline: 1.4194x; 1.4194x over previous
//
#include <hip/hip_runtime.h>

typedef __bf16 bf16_t;
typedef bf16_t bf16x8 __attribute__((ext_vector_type(8)));
typedef bf16_t bf16x4 __attribute__((ext_vector_type(4)));
typedef float f32x4 __attribute__((ext_vector_type(4)));
typedef unsigned short u16;
typedef unsigned int u32;

#define E_TOT 524288
#define BM 128
#define NBLK (E_TOT / BM)   // 4096

__device__ __forceinline__ u16 f2bf(float f) {
  u32 u = __builtin_bit_cast(u32, f);
  u += 0x7FFFu + ((u >> 16) & 1u);
  return (u16)(u >> 16);
}

__device__ __forceinline__ bf16x8 pack8(f32x4 a, f32x4 b) {
  bf16x8 p;
  p[0] = (bf16_t)a[0]; p[1] = (bf16_t)a[1]; p[2] = (bf16_t)a[2]; p[3] = (bf16_t)a[3];
  p[4] = (bf16_t)b[0]; p[5] = (bf16_t)b[1]; p[6] = (bf16_t)b[2]; p[7] = (bf16_t)b[3];
  return p;
}

__device__ __forceinline__ void gload_lds16(const void* g, void* l) {
  __builtin_amdgcn_global_load_lds(
      (const __attribute__((address_space(1))) u32*)g,
      (__attribute__((address_space(3))) u32*)l, 16, 0, 0);
}

// W1c: 6 chunks (BK=64). 16B-unit pos within chunk = n*8 + (j ^ (n&7));
// content = W1^T[n][kb*64 + j*8 + e]  (swizzle baked for linear gload_lds)
__global__ void prep_w1c(const float* __restrict__ W1, u16* __restrict__ W1c) {
  int t = blockIdx.x * 256 + threadIdx.x;  // 0..98303
  if (t < 98304) {
    int e = t & 7;
    int U = t >> 3;
    int kb = U >> 11, rem = U & 2047;
    int n = rem >> 3, jswz = rem & 7;
    int j = jswz ^ (n & 7);
    int k = kb * 64 + j * 8 + e;
    W1c[t] = f2bf(W1[k * 256 + n]);
  }
}

// W2F frag-ordered (epilogue register B-frags): idx = ((ks*4+n2f)*64+l)*8+e
//   holds W2^T[n2=n2f*16+(l&15)][k=ks*32+(l>>4)*8+e] = W2[k*64+n2]
__global__ void prep_w2f(const float* __restrict__ W2, u16* __restrict__ W2F) {
  int t = blockIdx.x * 256 + threadIdx.x;  // 0..16383
  if (t < 16384) {
    int e   = t & 7;
    int l   = (t >> 3) & 63;
    int n2f = (t >> 9) & 3;
    int ks  = t >> 11;
    int n2 = n2f * 16 + (l & 15);
    int k  = ks * 32 + ((l >> 4) << 3) + e;
    W2F[t] = f2bf(W2[k * 64 + n2]);
  }
}

// Fused: x = [src|dest|edge|u[batch]] (E x 384); h = relu(x@W1+b1); out = h@W2+b2
// 8-wave 2-phase-per-K-step interleaved pipeline; swapped MFMA -> h^T frags.
__global__ void __launch_bounds__(512) edge_fused(
    const float* __restrict__ src, const float* __restrict__ dst,
    const float* __restrict__ ea, const float* __restrict__ u,
    const int* __restrict__ batch, const u16* __restrict__ W1c,
    const float* __restrict__ b1, const u16* __restrict__ W2F,
    const float* __restrict__ b2, float* __restrict__ out)
{
  // LDS 98304 B (u16 units): A0@0 (8192), A1@8192, W0@16384 (16384), W1b@32768.
  // Epilogue: Hs[128][256] (32768 u16) overlays A0/A1/W0.
  __shared__ __align__(16) u16 smem[49152];
  u16* Hs = smem;

  const int t    = threadIdx.x;
  const int wid  = t >> 6;
  const int lane = t & 63;
  const int lr   = lane & 15;
  const int lg   = lane >> 4;
  const int wr   = wid >> 2;      // 0..1 : 64-row half
  const int wc   = wid & 3;       // 0..3 : 64-col slice of HIDDEN
  const int bid  = blockIdx.x;
  const int e0   = ((bid & 7) * 512 + (bid >> 3)) * BM;   // XCD swizzle (4096%8==0)
  const int r    = t >> 2;        // A row owned by this thread (0..127)
  const int jc   = t & 3;         // 16-f32 col group within 64-k chunk
  const int j0   = 2 * jc;        // two 16B units per thread
  const int bidx = batch[e0 + r];

  auto loadA = [&](int c, f32x4* s) {   // c compile-time
    const float* p;
    if (c < 2)       p = src + (size_t)(e0 + r) * 128 + c * 64 + jc * 16;
    else if (c < 4)  p = dst + (size_t)(e0 + r) * 128 + (c - 2) * 64 + jc * 16;
    else if (c == 4) p = ea + (size_t)(e0 + r) * 64 + jc * 16;
    else             p = u + (size_t)bidx * 64 + jc * 16;
    s[0] = *(const f32x4*)p;
    s[1] = *(const f32x4*)(p + 4);
    s[2] = *(const f32x4*)(p + 8);
    s[3] = *(const f32x4*)(p + 12);
  };
  auto issueW = [&](int c, u16* Wn) {   // 4 glds/wave, 32KB total
    #pragma unroll
    for (int g = 0; g < 4; ++g) {
      int ub = wid * 256 + g * 64;      // wave-uniform unit base
      gload_lds16(W1c + ((size_t)c * 2048 + ub + lane) * 8, Wn + ub * 8);
    }
  };
  auto packWrite = [&](f32x4* s, u16* An) {
    bf16x8 lo = pack8(s[0], s[1]);
    bf16x8 hi = pack8(s[2], s[3]);
    *(bf16x8*)&An[(r * 8 + (j0 ^ (r & 7))) * 8]       = lo;
    *(bf16x8*)&An[(r * 8 + ((j0 + 1) ^ (r & 7))) * 8] = hi;
  };

  // ---- prologue: establish steady invariant (only A(2) outstanding) ----
  f32x4 aset[3][4];
  loadA(0, aset[0]);
  loadA(1, aset[1]);
  issueW(0, smem + 16384);
  loadA(2, aset[2]);
  asm volatile("s_waitcnt vmcnt(12)" ::: "memory");   // A(0) arrived
  packWrite(aset[0], smem);                           // A_lds[0]
  asm volatile("s_waitcnt vmcnt(4)" ::: "memory");    // A(1)+W(0) arrived
  asm volatile("s_waitcnt lgkmcnt(0)" ::: "memory");
  __builtin_amdgcn_sched_barrier(0);
  __builtin_amdgcn_s_barrier();                       // publish A(0)+W(0)

  f32x4 acc[4][4];   // [nf][mf] h^T frags
  #pragma unroll
  for (int i = 0; i < 4; ++i)
    #pragma unroll
    for (int j = 0; j < 4; ++j)
      acc[i][j] = (f32x4){0.f, 0.f, 0.f, 0.f};

  // ---- K loop: 6 K-steps x 2 phases ----
  #pragma unroll
  for (int kb = 0; kb < 6; ++kb) {
    u16* Ab = smem + ((kb & 1) << 13);
    u16* An = smem + (((kb + 1) & 1) << 13);
    u16* Wb = smem + 16384 + ((kb & 1) << 14);
    u16* Wn = smem + 16384 + (((kb + 1) & 1) << 14);

    // ======== phase 0: af(8) + wf01(4) ds_reads || issue W(kb+1) ========
    bf16x8 af[2][4];
    #pragma unroll
    for (int ks = 0; ks < 2; ++ks)
      #pragma unroll
      for (int mf = 0; mf < 4; ++mf) {
        int row = wr * 64 + mf * 16 + lr;
        af[ks][mf] = *(const bf16x8*)&Ab[(row * 8 + ((ks * 4 + lg) ^ (row & 7))) * 8];
      }
    bf16x8 wf0[2][2];
    #pragma unroll
    for (int ks = 0; ks < 2; ++ks)
      #pragma unroll
      for (int nfi = 0; nfi < 2; ++nfi) {
        int n = wc * 64 + nfi * 16 + lr;
        wf0[ks][nfi] = *(const bf16x8*)&Wb[(n * 8 + ((ks * 4 + lg) ^ (n & 7))) * 8];
      }
    if (kb < 5) issueW(kb + 1, Wn);

    asm volatile("s_waitcnt lgkmcnt(0)" ::: "memory");
    __builtin_amdgcn_sched_barrier(0);
    __builtin_amdgcn_s_barrier();
    __builtin_amdgcn_s_setprio(1);
    #pragma unroll
    for (int nfi = 0; nfi < 2; ++nfi)
      #pragma unroll
      for (int ks = 0; ks < 2; ++ks)
        #pragma unroll
        for (int mf = 0; mf < 4; ++mf)
          acc[nfi][mf] = __builtin_amdgcn_mfma_f32_16x16x32_bf16(wf0[ks][nfi], af[ks][mf], acc[nfi][mf], 0, 0, 0);
    __builtin_amdgcn_s_setprio(0);
    __builtin_amdgcn_s_barrier();

    // ======== phase 1: wf23(4) ds_reads || pack+write A(kb+1) || issue A(kb+3) ========
    bf16x8 wf1[2][2];
    #pragma unroll
    for (int ks = 0; ks < 2; ++ks)
      #pragma unroll
      for (int nfi = 0; nfi < 2; ++nfi) {
        int n = wc * 64 + (2 + nfi) * 16 + lr;
        wf1[ks][nfi] = *(const bf16x8*)&Wb[(n * 8 + ((ks * 4 + lg) ^ (n & 7))) * 8];
      }
    if (kb < 5) packWrite(aset[(kb + 1) % 3], An);   // regs retired by prior gates
    if (kb < 3) loadA(kb + 3, aset[(kb + 3) % 3]);

    // gate W(kb+1) (and aged A) before the barrier so next ph0 reads are valid
    if (kb < 3)      asm volatile("s_waitcnt vmcnt(4)" ::: "memory");
    else if (kb < 5) asm volatile("s_waitcnt vmcnt(0)" ::: "memory");
    asm volatile("s_waitcnt lgkmcnt(0)" ::: "memory");
    __builtin_amdgcn_sched_barrier(0);
    __builtin_amdgcn_s_barrier();
    __builtin_amdgcn_s_setprio(1);
    #pragma unroll
    for (int nfi = 0; nfi < 2; ++nfi)
      #pragma unroll
      for (int ks = 0; ks < 2; ++ks)
        #pragma unroll
        for (int mf = 0; mf < 4; ++mf)
          acc[2 + nfi][mf] = __builtin_amdgcn_mfma_f32_16x16x32_bf16(wf1[ks][nfi], af[ks][mf], acc[2 + nfi][mf], 0, 0, 0);
    __builtin_amdgcn_s_setprio(0);
    __builtin_amdgcn_s_barrier();
  }

  // ---- h^T -> Hs[128][256] bf16 (overlays K-loop bufs; last barrier guards) ----
  #pragma unroll
  for (int nf = 0; nf < 4; ++nf) {
    f32x4 b1v = *(const f32x4*)(b1 + wc * 64 + nf * 16 + lg * 4);
    #pragma unroll
    for (int mf = 0; mf < 4; ++mf) {
      bf16x4 hb;
      #pragma unroll
      for (int rr = 0; rr < 4; ++rr)
        hb[rr] = (bf16_t)fmaxf(acc[nf][mf][rr] + b1v[rr], 0.f);
      int row = wr * 64 + mf * 16 + lr;
      int uu = (wc * 4 + nf) * 4 + lg;
      int up = uu ^ ((lr & 3) << 2);
      *(bf16x4*)&Hs[row * 256 + up * 4] = hb;
    }
  }
  asm volatile("s_waitcnt lgkmcnt(0)" ::: "memory");
  __builtin_amdgcn_sched_barrier(0);
  __builtin_amdgcn_s_barrier();

  // ---- layer 2: out^T frags = mfma(W2_frag, h_frag); W2F from L1/L2 ----
  const int row2 = wid * 16 + lr;        // 8 waves cover 128 rows
  f32x4 d2[4];
  #pragma unroll
  for (int i = 0; i < 4; ++i) d2[i] = (f32x4){0.f, 0.f, 0.f, 0.f};
  #pragma unroll
  for (int ks = 0; ks < 8; ++ks) {
    int uu = ks * 8 + lg * 2;
    int up = uu ^ ((lr & 3) << 2);       // bit0 untouched -> b128 contiguous
    bf16x8 a2 = *(const bf16x8*)&Hs[row2 * 256 + up * 4];
    const u16* q = W2F + (size_t)ks * 2048 + lane * 8;
    #pragma unroll
    for (int n2f = 0; n2f < 4; ++n2f)
      d2[n2f] = __builtin_amdgcn_mfma_f32_16x16x32_bf16(
          *(const bf16x8*)(q + n2f * 512), a2, d2[n2f], 0, 0, 0);
  }

  #pragma unroll
  for (int n2f = 0; n2f < 4; ++n2f) {
    f32x4 b2v = *(const f32x4*)(b2 + n2f * 16 + lg * 4);
    f32x4 ov = d2[n2f] + b2v;
    *(f32x4*)&out[(size_t)(e0 + row2) * 64 + n2f * 16 + lg * 4] = ov;
  }
}

extern "C" void kernel_launch(void* const* d_in, const int* in_sizes, int n_in,
                              void* d_out, int out_size, void* d_ws, size_t ws_size,
                              hipStream_t stream) {
  const float* src  = (const float*)d_in[0];
  const float* dst  = (const float*)d_in[1];
  const float* ea   = (const float*)d_in[2];
  const float* u    = (const float*)d_in[3];
  const int* batch  = (const int*)d_in[4];
  const float* W1   = (const float*)d_in[5];
  const float* b1   = (const float*)d_in[6];
  const float* W2   = (const float*)d_in[7];
  const float* b2   = (const float*)d_in[8];
  float* out = (float*)d_out;

  u16* W1c = (u16*)d_ws;          // 98304 u16 (6 chunks, swizzle-baked W1^T)
  u16* W2F = W1c + 98304;         // 16384 u16 frag-ordered W2^T

  prep_w1c<<<384, 256, 0, stream>>>(W1, W1c);
  prep_w2f<<<64, 256, 0, stream>>>(W2, W2F);
  edge_fused<<<NBLK, 512, 0, stream>>>(src, dst, ea, u, batch, W1c, b1, W2F, b2, out);
}